// Round 1
// baseline (303.889 us; speedup 1.0000x reference)
//
#include <hip/hip_runtime.h>

// DIM=256 H=8 HD=32 W=64 N=8192 nw=128
// xyz: T=40, off=20, hi=39 ; rgb: T=32, off=16, hi=31
// table element ((c*T+t)*8+h)*32+d == r*256 + h*32 + d, r=c*T+t

typedef __attribute__((ext_vector_type(8))) short short8;
typedef __attribute__((ext_vector_type(4))) float f32x4;

__device__ __forceinline__ unsigned short f2bf(float f) {
    union { float f; unsigned int u; } v; v.f = f;
    unsigned int r = v.u + 0x7FFFu + ((v.u >> 16) & 1u);
    return (unsigned short)(r >> 16);
}

// Wave-local ordering fence: drains this wave's outstanding DS ops (so
// atomic->read / read->write / write->atomic on wave-private LDS rows are
// ordered) without a cross-wave barrier. "memory" clobber stops compiler
// reordering of LDS accesses across it.
#define LFENCE() asm volatile("s_waitcnt lgkmcnt(0)" ::: "memory")

// ---------------------------------------------------------------------------
// QKV GEMM (bf16 MFMA), fp32 inputs cast inline during staging. (unchanged)
// ---------------------------------------------------------------------------
__global__ __launch_bounds__(256) void k_qkv(
    const float* __restrict__ A, const float* __restrict__ B,
    const float* __restrict__ bias,
    ushort* __restrict__ qb, ushort* __restrict__ kb, ushort* __restrict__ vb)
{
    __shared__ __align__(16) ushort a_s[128 * 72];
    __shared__ __align__(16) ushort b_s[64 * 72];
    const int tid = threadIdx.x;
    const int m0 = blockIdx.y * 128;
    const int n0 = blockIdx.x * 64;
    const int w = tid >> 6, wm = w >> 1, wn = w & 1;
    const int l4 = tid & 15, quad = (tid >> 4) & 3;
    f32x4 acc[4][2];
#pragma unroll
    for (int mt = 0; mt < 4; ++mt)
#pragma unroll
        for (int nt = 0; nt < 2; ++nt) acc[mt][nt] = (f32x4){0.f, 0.f, 0.f, 0.f};

    for (int k0 = 0; k0 < 256; k0 += 64) {
#pragma unroll
        for (int l = 0; l < 4; ++l) {
            int e = tid + l * 256;
            int row = e >> 3, kq = e & 7;
            const float* ap = A + (size_t)(m0 + row) * 256 + k0 + kq * 8;
            float4 v0 = *(const float4*)ap, v1 = *(const float4*)(ap + 4);
            union { ushort u[8]; uint4 v; } pk;
            pk.u[0] = f2bf(v0.x); pk.u[1] = f2bf(v0.y); pk.u[2] = f2bf(v0.z); pk.u[3] = f2bf(v0.w);
            pk.u[4] = f2bf(v1.x); pk.u[5] = f2bf(v1.y); pk.u[6] = f2bf(v1.z); pk.u[7] = f2bf(v1.w);
            *(uint4*)&a_s[row * 72 + kq * 8] = pk.v;
        }
#pragma unroll
        for (int l = 0; l < 2; ++l) {
            int e = tid + l * 256;
            int row = e >> 3, kq = e & 7;
            const float* bp = B + (size_t)(n0 + row) * 256 + k0 + kq * 8;
            float4 v0 = *(const float4*)bp, v1 = *(const float4*)(bp + 4);
            union { ushort u[8]; uint4 v; } pk;
            pk.u[0] = f2bf(v0.x); pk.u[1] = f2bf(v0.y); pk.u[2] = f2bf(v0.z); pk.u[3] = f2bf(v0.w);
            pk.u[4] = f2bf(v1.x); pk.u[5] = f2bf(v1.y); pk.u[6] = f2bf(v1.z); pk.u[7] = f2bf(v1.w);
            *(uint4*)&b_s[row * 72 + kq * 8] = pk.v;
        }
        __syncthreads();
#pragma unroll
        for (int kh = 0; kh < 2; ++kh) {
            short8 bf0 = *(const short8*)&b_s[(wn * 32 + l4) * 72 + kh * 32 + quad * 8];
            short8 bf1 = *(const short8*)&b_s[(wn * 32 + 16 + l4) * 72 + kh * 32 + quad * 8];
#pragma unroll
            for (int mt = 0; mt < 4; ++mt) {
                short8 af = *(const short8*)&a_s[(wm * 64 + mt * 16 + l4) * 72 + kh * 32 + quad * 8];
                acc[mt][0] = __builtin_amdgcn_mfma_f32_16x16x32_bf16(af, bf0, acc[mt][0], 0, 0, 0);
                acc[mt][1] = __builtin_amdgcn_mfma_f32_16x16x32_bf16(af, bf1, acc[mt][1], 0, 0, 0);
            }
        }
        __syncthreads();
    }
#pragma unroll
    for (int nt = 0; nt < 2; ++nt) {
        int c = n0 + wn * 32 + nt * 16 + l4;
        float bv = bias[c];
        int s = c >> 8, rem = c & 255, h = rem >> 5, d = rem & 31;
        ushort* dst = (s == 0) ? qb : ((s == 1) ? kb : vb);
        float mul = (s == 0) ? 0.17677669529663687f : 1.0f;
#pragma unroll
        for (int mt = 0; mt < 4; ++mt) {
            int mbase = m0 + wm * 64 + mt * 16 + quad * 4;
#pragma unroll
            for (int reg = 0; reg < 4; ++reg) {
                int m = mbase + reg;
                int nw = m >> 6, ii = m & 63;
                dst[((size_t)((nw * 8 + h) * 64 + ii)) * 32 + d] = f2bf((acc[mt][nt][reg] + bv) * mul);
            }
        }
    }
}

// ---------------------------------------------------------------------------
// MFMA attention per (window, head).  Round-10: 4-blocks/CU restructure.
//
// WHY (round-10 theory): counters showed latency-bound (MfmaUtil 0.8%,
// VALUBusy 12.6%, HBM 0.9%) with LDS=55,296 B -> 2 blocks/CU, and grid =
// exactly 4 blocks/CU -> 2 lockstep rounds. 3-resident is useless
// (ceil(4/3)=2); 4-resident halves makespan. Fix: process the bias tables
// PER COORDINATE COMPONENT c, shrinking dbuf from [64][122] (31,232 B) to a
// single c-slice [64][41] (10,496 B). The bias/value-bias math is exactly
// separable over c (independent 40/32-bin contractions summed).
// LDS: dbuf 10,496 + U 22,528 + cwf 1,536 = 34,560 B -> 4 blocks/CU.
// __launch_bounds__(256,4): 512/4 = 128 VGPR cap = current usage.
// Spill tripwire: VGPR>128 or WRITE_SIZE >> 4 MB.
//
// Barrier discipline: dq-side gathers (useJ=false), all scatters, value-bias
// A-reads and bin zeroing touch ONLY wave-private dbuf rows (i/read-row in
// [w*16, w*16+16)) -> no __syncthreads, just LFENCE (own-wave DS drain).
// dk-side gathers (useJ=true) read all 64 j-rows -> real barriers.
// ---------------------------------------------------------------------------
#define DBS 41

__global__ __launch_bounds__(256, 4) void k_attn(
    const ushort* __restrict__ qb, const ushort* __restrict__ kb, const ushort* __restrict__ vb,
    const float* __restrict__ nco,
    const float* __restrict__ qxt, const float* __restrict__ kxt, const float* __restrict__ vxt,
    const float* __restrict__ qrt, const float* __restrict__ krt, const float* __restrict__ vrt,
    ushort* __restrict__ aout)
{
    __shared__ __align__(16) float dbuf[64 * DBS];   // 10,496 B: one c-slice of tgemm-out / bins
    __shared__ __align__(16) ushort U[11264];        // 22,528 B overlay region
    __shared__ __align__(16) float cwf[64 * 6];      // dedicated, alive all kernel
    // Phase A overlays:
    ushort* q_s  = U;              // [64][40]
    ushort* k_s  = U + 2560;       // [64][40]
    ushort* tbl  = U + 5120;       // [128][40]
    // Phase B overlays:
    ushort* attn_s = U;            // [64][72]
    ushort* v_t    = U + 4608;     // [32][72]
    ushort* vtbl   = U + 6912;     // [32][136]

    const int tid = threadIdx.x;
    const int n = blockIdx.x >> 3;
    const int h = blockIdx.x & 7;
    const int w = tid >> 6;
    const int lane = tid & 63;
    const int l4 = tid & 15;
    const int quad = (tid >> 4) & 3;

    const size_t base = (size_t)((n * 8 + h) * 64) * 32;

    // ---- stage q, k, coords ----
    {
        int row = tid >> 2, part = tid & 3;
        *(uint4*)&q_s[row * 40 + part * 8] = *(const uint4*)(qb + base + tid * 8);
        *(uint4*)&k_s[row * 40 + part * 8] = *(const uint4*)(kb + base + tid * 8);
    }
    if (tid < 64) {
        const float* cp = nco + (size_t)(n * 64 + tid) * 6;
        cwf[tid * 6 + 0] = cp[0] * 4.f; cwf[tid * 6 + 1] = cp[1] * 4.f;
        cwf[tid * 6 + 2] = cp[2] * 4.f; cwf[tid * 6 + 3] = cp[3] * 8.f;
        cwf[tid * 6 + 4] = cp[4] * 8.f; cwf[tid * 6 + 5] = cp[5] * 8.f;
    }

    auto stageTbl = [&](const float* tbg, int R, int Rpad) {
        for (int e = tid; e < R * 4; e += 256) {
            int r = e >> 2, part = e & 3;
            const float* src = tbg + (size_t)r * 256 + part * 8;
            float4 f0 = *(const float4*)src, f1 = *(const float4*)(src + 4);
            union { ushort u[8]; uint4 v; } pk;
            pk.u[0] = f2bf(f0.x); pk.u[1] = f2bf(f0.y); pk.u[2] = f2bf(f0.z); pk.u[3] = f2bf(f0.w);
            pk.u[4] = f2bf(f1.x); pk.u[5] = f2bf(f1.y); pk.u[6] = f2bf(f1.z); pk.u[7] = f2bf(f1.w);
            *(uint4*)&tbl[r * 40 + part * 8] = pk.v;
        }
        for (int e = tid; e < (Rpad - R) * 40; e += 256) tbl[R * 40 + e] = 0;
    };
    // No zero-pad needed: per-c value-bias reads only cols < c*T+T <= 120.
    auto stageVtbl = [&](const float* tbg, int R) {
        for (int e = tid; e < R * 4; e += 256) {
            int r = e >> 2, part = e & 3;
            const float* src = tbg + (size_t)r * 256 + part * 8;
            float4 f0 = *(const float4*)src, f1 = *(const float4*)(src + 4);
            int d0 = part * 8;
            vtbl[(d0 + 0) * 136 + r] = f2bf(f0.x);
            vtbl[(d0 + 1) * 136 + r] = f2bf(f0.y);
            vtbl[(d0 + 2) * 136 + r] = f2bf(f0.z);
            vtbl[(d0 + 3) * 136 + r] = f2bf(f0.w);
            vtbl[(d0 + 4) * 136 + r] = f2bf(f1.x);
            vtbl[(d0 + 5) * 136 + r] = f2bf(f1.y);
            vtbl[(d0 + 6) * 136 + r] = f2bf(f1.z);
            vtbl[(d0 + 7) * 136 + r] = f2bf(f1.w);
        }
    };
    auto stageVt = [&]() {
        int j = tid >> 2, d0 = (tid & 3) * 8;
        uint4 pk = *(const uint4*)(vb + base + tid * 8);
        const ushort* u = (const ushort*)&pk;
#pragma unroll
        for (int ii = 0; ii < 8; ++ii) v_t[(d0 + ii) * 72 + j] = u[ii];
    };

    float lg[4][4];   // [tt][reg]: row i = w*16+quad*4+reg, col j = tt*16+l4

    // table-GEMM for component c: contracts a_s rows with tbl rows
    // [c*T, c*T+T), writing the T local bins into dbuf cols [0, T).
    auto tgemmC = [&](const ushort* a_s, int c, int T) {
        short8 af = *(const short8*)&a_s[(w * 16 + l4) * 40 + quad * 8];
        const int NT = (T == 40) ? 3 : 2;
        for (int tt = 0; tt < NT; ++tt) {
            short8 bf = *(const short8*)&tbl[(c * T + tt * 16 + l4) * 40 + quad * 8];
            f32x4 a = {0.f, 0.f, 0.f, 0.f};
            a = __builtin_amdgcn_mfma_f32_16x16x32_bf16(af, bf, a, 0, 0, 0);
            int col = tt * 16 + l4;
            int rb = w * 16 + quad * 4;
            if (col < T) {
                dbuf[(rb + 0) * DBS + col] = a[0];
                dbuf[(rb + 1) * DBS + col] = a[1];
                dbuf[(rb + 2) * DBS + col] = a[2];
                dbuf[(rb + 3) * DBS + col] = a[3];
            }
        }
    };
    // Indices recomputed from cwf at every use site (no idx register arrays).
    auto gatherC = [&](int cc, int off, int hi, bool useJ) {
#pragma unroll
        for (int tt = 0; tt < 4; ++tt) {
            int j = tt * 16 + l4;
            float cj = cwf[j * 6 + cc];
#pragma unroll
            for (int reg = 0; reg < 4; ++reg) {
                int i = w * 16 + quad * 4 + reg;
                int x = min(max((int)floorf(cwf[i * 6 + cc] - cj) + off, 0), hi);
                lg[tt][reg] += dbuf[(useJ ? j : i) * DBS + x];
            }
        }
    };
    auto scatterC = [&](int cc, int off, int hi) {
#pragma unroll
        for (int tt = 0; tt < 4; ++tt) {
            int j = tt * 16 + l4;
            float cj = cwf[j * 6 + cc];
#pragma unroll
            for (int reg = 0; reg < 4; ++reg) {
                int i = w * 16 + quad * 4 + reg;
                int x = min(max((int)floorf(cwf[i * 6 + cc] - cj) + off, 0), hi);
                atomicAdd(&dbuf[i * DBS + x], lg[tt][reg]);
            }
        }
    };
    // zero this wave's 16 bin rows only (wave-private)
    auto zeroOwn = [&]() {
        float* rb = &dbuf[w * 16 * DBS];
        for (int e = lane; e < 16 * DBS; e += 64) rb[e] = 0.f;
    };

    stageTbl(kxt + h * 32, 120, 128);
    __syncthreads();

    // ---- QK logits ----
    {
        short8 aq = *(const short8*)&q_s[(w * 16 + l4) * 40 + quad * 8];
#pragma unroll
        for (int tt = 0; tt < 4; ++tt) {
            short8 bk = *(const short8*)&k_s[(tt * 16 + l4) * 40 + quad * 8];
            f32x4 r = {0.f, 0.f, 0.f, 0.f};
            r = __builtin_amdgcn_mfma_f32_16x16x32_bf16(aq, bk, r, 0, 0, 0);
            lg[tt][0] = r[0]; lg[tt][1] = r[1]; lg[tt][2] = r[2]; lg[tt][3] = r[3];
        }
    }

    // ---- dk (bias_k): cross-wave j-row gathers -> real barriers ----
    tgemmC(k_s, 0, 40);
    __syncthreads();
    gatherC(0, 20, 39, true);
    __syncthreads();
    tgemmC(k_s, 1, 40);
    __syncthreads();
    gatherC(1, 20, 39, true);
    __syncthreads();
    tgemmC(k_s, 2, 40);
    __syncthreads();
    gatherC(2, 20, 39, true);
    stageTbl(krt + h * 32, 96, 96);
    __syncthreads();
    tgemmC(k_s, 0, 32);
    __syncthreads();
    gatherC(3, 16, 31, true);
    __syncthreads();
    tgemmC(k_s, 1, 32);
    __syncthreads();
    gatherC(4, 16, 31, true);
    __syncthreads();
    tgemmC(k_s, 2, 32);
    __syncthreads();
    gatherC(5, 16, 31, true);
    stageTbl(qxt + h * 32, 120, 128);
    __syncthreads();

    // ---- dq (bias_q): wave-private i-rows -> fences only ----
    tgemmC(q_s, 0, 40); LFENCE();
    gatherC(0, 20, 39, false); LFENCE();
    tgemmC(q_s, 1, 40); LFENCE();
    gatherC(1, 20, 39, false); LFENCE();
    tgemmC(q_s, 2, 40);
    __syncthreads();                       // others must finish reading tbl
    gatherC(2, 20, 39, false);
    stageTbl(qrt + h * 32, 96, 96);
    __syncthreads();
    tgemmC(q_s, 0, 32); LFENCE();
    gatherC(3, 16, 31, false); LFENCE();
    tgemmC(q_s, 1, 32); LFENCE();
    gatherC(4, 16, 31, false); LFENCE();
    tgemmC(q_s, 2, 32);
    __syncthreads();                       // tbl/k_s regions go dead here
    gatherC(5, 16, 31, false);
    stageVtbl(vxt + h * 32, 120);
    stageVt();
    __syncthreads();

    // ---- softmax ----
#pragma unroll
    for (int reg = 0; reg < 4; ++reg) {
        float m = fmaxf(fmaxf(lg[0][reg], lg[1][reg]), fmaxf(lg[2][reg], lg[3][reg]));
        m = fmaxf(m, __shfl_xor(m, 1));
        m = fmaxf(m, __shfl_xor(m, 2));
        m = fmaxf(m, __shfl_xor(m, 4));
        m = fmaxf(m, __shfl_xor(m, 8));
        float s = 0.f;
#pragma unroll
        for (int tt = 0; tt < 4; ++tt) { lg[tt][reg] = __expf(lg[tt][reg] - m); s += lg[tt][reg]; }
        s += __shfl_xor(s, 1); s += __shfl_xor(s, 2);
        s += __shfl_xor(s, 4); s += __shfl_xor(s, 8);
        float inv = 1.f / s;
#pragma unroll
        for (int tt = 0; tt < 4; ++tt) lg[tt][reg] *= inv;
    }
#pragma unroll
    for (int tt = 0; tt < 4; ++tt)
#pragma unroll
        for (int reg = 0; reg < 4; ++reg)
            attn_s[(w * 16 + quad * 4 + reg) * 72 + tt * 16 + l4] = f2bf(lg[tt][reg]);
    zeroOwn();
    __syncthreads();

    // ---- AV ----
    f32x4 acc0 = {0.f, 0.f, 0.f, 0.f}, acc1 = {0.f, 0.f, 0.f, 0.f};
#pragma unroll
    for (int s = 0; s < 2; ++s) {
        short8 af = *(const short8*)&attn_s[(w * 16 + l4) * 72 + s * 32 + quad * 8];
        short8 b0 = *(const short8*)&v_t[l4 * 72 + s * 32 + quad * 8];
        short8 b1 = *(const short8*)&v_t[(16 + l4) * 72 + s * 32 + quad * 8];
        acc0 = __builtin_amdgcn_mfma_f32_16x16x32_bf16(af, b0, acc0, 0, 0, 0);
        acc1 = __builtin_amdgcn_mfma_f32_16x16x32_bf16(af, b1, acc1, 0, 0, 0);
    }

    // value-bias contraction for component c: bins cols [0,T) x vtbl cols
    // [c*T, c*T+T). A-frag rows are wave-private.
    auto atgemmC = [&](int c, int T, int S) {
#pragma unroll
        for (int s = 0; s < S; ++s) {
            int koff = s * 32 + quad * 8;
            short8 af = {0, 0, 0, 0, 0, 0, 0, 0};
            int kr = 0;
            if (koff < T) {
                const float* ap = &dbuf[(w * 16 + l4) * DBS + koff];
#pragma unroll
                for (int ii = 0; ii < 8; ++ii) af[ii] = (short)f2bf(ap[ii]);
                kr = c * T + koff;
            }
            short8 b0 = *(const short8*)&vtbl[l4 * 136 + kr];
            short8 b1 = *(const short8*)&vtbl[(16 + l4) * 136 + kr];
            acc0 = __builtin_amdgcn_mfma_f32_16x16x32_bf16(af, b0, acc0, 0, 0, 0);
            acc1 = __builtin_amdgcn_mfma_f32_16x16x32_bf16(af, b1, acc1, 0, 0, 0);
        }
    };

    // ---- value-bias xyz: all dbuf traffic wave-private -> fences only ----
    scatterC(0, 20, 39); LFENCE();
    atgemmC(0, 40, 2); LFENCE();
    zeroOwn(); LFENCE();
    scatterC(1, 20, 39); LFENCE();
    atgemmC(1, 40, 2); LFENCE();
    zeroOwn(); LFENCE();
    scatterC(2, 20, 39); LFENCE();
    atgemmC(2, 40, 2);
    __syncthreads();                       // all waves done reading vtbl(vxt)
    zeroOwn();
    stageVtbl(vrt + h * 32, 96);
    __syncthreads();

    // ---- value-bias rgb ----
    scatterC(3, 16, 31); LFENCE();
    atgemmC(0, 32, 1); LFENCE();
    zeroOwn(); LFENCE();
    scatterC(4, 16, 31); LFENCE();
    atgemmC(1, 32, 1); LFENCE();
    zeroOwn(); LFENCE();
    scatterC(5, 16, 31); LFENCE();
    atgemmC(2, 32, 1);

    // ---- epilogue: bf16 ao[i][h*32+d] ----
    {
        ushort* op = aout + (size_t)(n * 64 + w * 16 + quad * 4) * 256 + h * 32;
#pragma unroll
        for (int reg = 0; reg < 4; ++reg) {
            op[reg * 256 + l4] = f2bf(acc0[reg]);
            op[reg * 256 + 16 + l4] = f2bf(acc1[reg]);
        }
    }
}

// ---------------------------------------------------------------------------
// Proj GEMM (bf16 MFMA): out = ao(bf16) @ proj_w(fp32, cast inline)^T + pb
// ---------------------------------------------------------------------------
__global__ __launch_bounds__(256) void k_proj(
    const ushort* __restrict__ A, const float* __restrict__ B,
    const float* __restrict__ bias, float* __restrict__ out)
{
    __shared__ __align__(16) ushort a_s[128 * 72];
    __shared__ __align__(16) ushort b_s[64 * 72];
    const int tid = threadIdx.x;
    const int m0 = blockIdx.y * 128;
    const int n0 = blockIdx.x * 64;
    const int w = tid >> 6, wm = w >> 1, wn = w & 1;
    const int l4 = tid & 15, quad = (tid >> 4) & 3;
    f32x4 acc[4][2];
#pragma unroll
    for (int mt = 0; mt < 4; ++mt)
#pragma unroll
        for (int nt = 0; nt < 2; ++nt) acc[mt][nt] = (f32x4){0.f, 0.f, 0.f, 0.f};

    for (int k0 = 0; k0 < 256; k0 += 64) {
#pragma unroll
        for (int l = 0; l < 4; ++l) {
            int e = tid + l * 256;
            int row = e >> 3, kq = e & 7;
            *(uint4*)&a_s[row * 72 + kq * 8] =
                *(const uint4*)(A + (size_t)(m0 + row) * 256 + k0 + kq * 8);
        }
#pragma unroll
        for (int l = 0; l < 2; ++l) {
            int e = tid + l * 256;
            int row = e >> 3, kq = e & 7;
            const float* bp = B + (size_t)(n0 + row) * 256 + k0 + kq * 8;
            float4 v0 = *(const float4*)bp, v1 = *(const float4*)(bp + 4);
            union { ushort u[8]; uint4 v; } pk;
            pk.u[0] = f2bf(v0.x); pk.u[1] = f2bf(v0.y); pk.u[2] = f2bf(v0.z); pk.u[3] = f2bf(v0.w);
            pk.u[4] = f2bf(v1.x); pk.u[5] = f2bf(v1.y); pk.u[6] = f2bf(v1.z); pk.u[7] = f2bf(v1.w);
            *(uint4*)&b_s[row * 72 + kq * 8] = pk.v;
        }
        __syncthreads();
#pragma unroll
        for (int kh = 0; kh < 2; ++kh) {
            short8 bf0 = *(const short8*)&b_s[(wn * 32 + l4) * 72 + kh * 32 + quad * 8];
            short8 bf1 = *(const short8*)&b_s[(wn * 32 + 16 + l4) * 72 + kh * 32 + quad * 8];
#pragma unroll
            for (int mt = 0; mt < 4; ++mt) {
                short8 af = *(const short8*)&a_s[(wm * 64 + mt * 16 + l4) * 72 + kh * 32 + quad * 8];
                acc[mt][0] = __builtin_amdgcn_mfma_f32_16x16x32_bf16(af, bf0, acc[mt][0], 0, 0, 0);
                acc[mt][1] = __builtin_amdgcn_mfma_f32_16x16x32_bf16(af, bf1, acc[mt][1], 0, 0, 0);
            }
        }
        __syncthreads();
    }
#pragma unroll
    for (int nt = 0; nt < 2; ++nt) {
        int c = n0 + wn * 32 + nt * 16 + l4;
        float bv = bias[c];
#pragma unroll
        for (int mt = 0; mt < 4; ++mt) {
            int mbase = m0 + wm * 64 + mt * 16 + quad * 4;
#pragma unroll
            for (int reg = 0; reg < 4; ++reg)
                out[(size_t)(mbase + reg) * 256 + c] = acc[mt][nt][reg] + bv;
        }
    }
}

extern "C" void kernel_launch(void* const* d_in, const int* in_sizes, int n_in,
                              void* d_out, int out_size, void* d_ws, size_t ws_size,
                              hipStream_t stream)
{
    const float* feats = (const float*)d_in[0];
    const float* nco   = (const float*)d_in[1];
    const float* qkvw  = (const float*)d_in[2];
    const float* qkvb  = (const float*)d_in[3];
    const float* qxt   = (const float*)d_in[4];
    const float* kxt   = (const float*)d_in[5];
    const float* vxt   = (const float*)d_in[6];
    const float* qrt   = (const float*)d_in[7];
    const float* krt   = (const float*)d_in[8];
    const float* vrt   = (const float*)d_in[9];
    const float* pw    = (const float*)d_in[10];
    const float* pb    = (const float*)d_in[11];
    float* out = (float*)d_out;

    ushort* qb  = (ushort*)d_ws;                       // [128][8][64][32] bf16
    ushort* kb  = qb + (size_t)2097152;
    ushort* vb  = kb + (size_t)2097152;
    ushort* aob = vb + (size_t)2097152;                // [8192][256] bf16

    k_qkv<<<dim3(12, 64), 256, 0, stream>>>(feats, qkvw, qkvb, qb, kb, vb);
    k_attn<<<dim3(1024), 256, 0, stream>>>(qb, kb, vb, nco, qxt, kxt, vxt, qrt, krt, vrt, aob);
    k_proj<<<dim3(4, 64), 256, 0, stream>>>(aob, pw, pb, out);
}

// Round 3
// 273.324 us; speedup vs baseline: 1.1118x; 1.1118x over previous
//
#include <hip/hip_runtime.h>

// DIM=256 H=8 HD=32 W=64 N=8192 nw=128
// xyz: T=40, off=20, hi=39 ; rgb: T=32, off=16, hi=31
// table element ((c*T+t)*8+h)*32+d == r*256 + h*32 + d, r=c*T+t

typedef __attribute__((ext_vector_type(8))) short short8;
typedef __attribute__((ext_vector_type(4))) float f32x4;

__device__ __forceinline__ unsigned short f2bf(float f) {
    union { float f; unsigned int u; } v; v.f = f;
    unsigned int r = v.u + 0x7FFFu + ((v.u >> 16) & 1u);
    return (unsigned short)(r >> 16);
}

// Wave-local ordering fence: drains this wave's outstanding DS ops (so
// atomic->read / read->write / write->atomic on wave-private LDS rows are
// ordered) without a cross-wave barrier. "memory" clobber stops compiler
// reordering of LDS accesses across it.
#define LFENCE() asm volatile("s_waitcnt lgkmcnt(0)" ::: "memory")

// ---------------------------------------------------------------------------
// QKV GEMM (bf16 MFMA), fp32 inputs cast inline during staging. (unchanged)
// ---------------------------------------------------------------------------
__global__ __launch_bounds__(256) void k_qkv(
    const float* __restrict__ A, const float* __restrict__ B,
    const float* __restrict__ bias,
    ushort* __restrict__ qb, ushort* __restrict__ kb, ushort* __restrict__ vb)
{
    __shared__ __align__(16) ushort a_s[128 * 72];
    __shared__ __align__(16) ushort b_s[64 * 72];
    const int tid = threadIdx.x;
    const int m0 = blockIdx.y * 128;
    const int n0 = blockIdx.x * 64;
    const int w = tid >> 6, wm = w >> 1, wn = w & 1;
    const int l4 = tid & 15, quad = (tid >> 4) & 3;
    f32x4 acc[4][2];
#pragma unroll
    for (int mt = 0; mt < 4; ++mt)
#pragma unroll
        for (int nt = 0; nt < 2; ++nt) acc[mt][nt] = (f32x4){0.f, 0.f, 0.f, 0.f};

    for (int k0 = 0; k0 < 256; k0 += 64) {
#pragma unroll
        for (int l = 0; l < 4; ++l) {
            int e = tid + l * 256;
            int row = e >> 3, kq = e & 7;
            const float* ap = A + (size_t)(m0 + row) * 256 + k0 + kq * 8;
            float4 v0 = *(const float4*)ap, v1 = *(const float4*)(ap + 4);
            union { ushort u[8]; uint4 v; } pk;
            pk.u[0] = f2bf(v0.x); pk.u[1] = f2bf(v0.y); pk.u[2] = f2bf(v0.z); pk.u[3] = f2bf(v0.w);
            pk.u[4] = f2bf(v1.x); pk.u[5] = f2bf(v1.y); pk.u[6] = f2bf(v1.z); pk.u[7] = f2bf(v1.w);
            *(uint4*)&a_s[row * 72 + kq * 8] = pk.v;
        }
#pragma unroll
        for (int l = 0; l < 2; ++l) {
            int e = tid + l * 256;
            int row = e >> 3, kq = e & 7;
            const float* bp = B + (size_t)(n0 + row) * 256 + k0 + kq * 8;
            float4 v0 = *(const float4*)bp, v1 = *(const float4*)(bp + 4);
            union { ushort u[8]; uint4 v; } pk;
            pk.u[0] = f2bf(v0.x); pk.u[1] = f2bf(v0.y); pk.u[2] = f2bf(v0.z); pk.u[3] = f2bf(v0.w);
            pk.u[4] = f2bf(v1.x); pk.u[5] = f2bf(v1.y); pk.u[6] = f2bf(v1.z); pk.u[7] = f2bf(v1.w);
            *(uint4*)&b_s[row * 72 + kq * 8] = pk.v;
        }
        __syncthreads();
#pragma unroll
        for (int kh = 0; kh < 2; ++kh) {
            short8 bf0 = *(const short8*)&b_s[(wn * 32 + l4) * 72 + kh * 32 + quad * 8];
            short8 bf1 = *(const short8*)&b_s[(wn * 32 + 16 + l4) * 72 + kh * 32 + quad * 8];
#pragma unroll
            for (int mt = 0; mt < 4; ++mt) {
                short8 af = *(const short8*)&a_s[(wm * 64 + mt * 16 + l4) * 72 + kh * 32 + quad * 8];
                acc[mt][0] = __builtin_amdgcn_mfma_f32_16x16x32_bf16(af, bf0, acc[mt][0], 0, 0, 0);
                acc[mt][1] = __builtin_amdgcn_mfma_f32_16x16x32_bf16(af, bf1, acc[mt][1], 0, 0, 0);
            }
        }
        __syncthreads();
    }
#pragma unroll
    for (int nt = 0; nt < 2; ++nt) {
        int c = n0 + wn * 32 + nt * 16 + l4;
        float bv = bias[c];
        int s = c >> 8, rem = c & 255, h = rem >> 5, d = rem & 31;
        ushort* dst = (s == 0) ? qb : ((s == 1) ? kb : vb);
        float mul = (s == 0) ? 0.17677669529663687f : 1.0f;
#pragma unroll
        for (int mt = 0; mt < 4; ++mt) {
            int mbase = m0 + wm * 64 + mt * 16 + quad * 4;
#pragma unroll
            for (int reg = 0; reg < 4; ++reg) {
                int m = mbase + reg;
                int nw = m >> 6, ii = m & 63;
                dst[((size_t)((nw * 8 + h) * 64 + ii)) * 32 + d] = f2bf((acc[mt][nt][reg] + bv) * mul);
            }
        }
    }
}

// ---------------------------------------------------------------------------
// MFMA attention per (window, head).  Round-11: 4-blocks/CU, natural regalloc.
//
// Round-10 post-mortem: __launch_bounds__(256,4) (total cap 128 on the
// unified VGPR+AGPR file) made the allocator split ~64 arch + 64 acc and
// spill massively (VGPR_Count=64, WRITE_SIZE 4->117 MB, FETCH 7.4->65 MB;
// the 185 MB of scratch traffic at ~0.94 TB/s IS the 202 us). Occupancy DID
// reach 38.7% — the structure works; only the forced cap was wrong.
// Round-0 evidence: natural allocation under a 256 cap is 128 total regs ->
// 4 waves/SIMD fit by VGPR anyway. With LDS at 34,560 B (4 blocks/CU) the
// occupancy limiter is min(LDS:4 blocks, VGPR:512/128=4 waves/SIMD) = 4
// blocks/CU WITHOUT coercion. So: launch_bounds(256,2) (same as round-0),
// keep the per-component low-LDS structure.
// Spill tripwire: VGPR_Count != ~128 or WRITE_SIZE >> 4 MB.
// LDS: dbuf 10,496 + U 22,528 + cwf 1,536 = 34,560 B.
//
// Barrier discipline: dq-side gathers (useJ=false), all scatters, value-bias
// A-reads and bin zeroing touch ONLY wave-private dbuf rows (i/read-row in
// [w*16, w*16+16)) -> no __syncthreads, just LFENCE (own-wave DS drain).
// dk-side gathers (useJ=true) read all 64 j-rows -> real barriers.
// ---------------------------------------------------------------------------
#define DBS 41

__global__ __launch_bounds__(256, 2) void k_attn(
    const ushort* __restrict__ qb, const ushort* __restrict__ kb, const ushort* __restrict__ vb,
    const float* __restrict__ nco,
    const float* __restrict__ qxt, const float* __restrict__ kxt, const float* __restrict__ vxt,
    const float* __restrict__ qrt, const float* __restrict__ krt, const float* __restrict__ vrt,
    ushort* __restrict__ aout)
{
    __shared__ __align__(16) float dbuf[64 * DBS];   // 10,496 B: one c-slice of tgemm-out / bins
    __shared__ __align__(16) ushort U[11264];        // 22,528 B overlay region
    __shared__ __align__(16) float cwf[64 * 6];      // dedicated, alive all kernel
    // Phase A overlays:
    ushort* q_s  = U;              // [64][40]
    ushort* k_s  = U + 2560;       // [64][40]
    ushort* tbl  = U + 5120;       // [128][40]
    // Phase B overlays:
    ushort* attn_s = U;            // [64][72]
    ushort* v_t    = U + 4608;     // [32][72]
    ushort* vtbl   = U + 6912;     // [32][136]

    const int tid = threadIdx.x;
    const int n = blockIdx.x >> 3;
    const int h = blockIdx.x & 7;
    const int w = tid >> 6;
    const int lane = tid & 63;
    const int l4 = tid & 15;
    const int quad = (tid >> 4) & 3;

    const size_t base = (size_t)((n * 8 + h) * 64) * 32;

    // ---- stage q, k, coords ----
    {
        int row = tid >> 2, part = tid & 3;
        *(uint4*)&q_s[row * 40 + part * 8] = *(const uint4*)(qb + base + tid * 8);
        *(uint4*)&k_s[row * 40 + part * 8] = *(const uint4*)(kb + base + tid * 8);
    }
    if (tid < 64) {
        const float* cp = nco + (size_t)(n * 64 + tid) * 6;
        cwf[tid * 6 + 0] = cp[0] * 4.f; cwf[tid * 6 + 1] = cp[1] * 4.f;
        cwf[tid * 6 + 2] = cp[2] * 4.f; cwf[tid * 6 + 3] = cp[3] * 8.f;
        cwf[tid * 6 + 4] = cp[4] * 8.f; cwf[tid * 6 + 5] = cp[5] * 8.f;
    }

    auto stageTbl = [&](const float* tbg, int R, int Rpad) {
        for (int e = tid; e < R * 4; e += 256) {
            int r = e >> 2, part = e & 3;
            const float* src = tbg + (size_t)r * 256 + part * 8;
            float4 f0 = *(const float4*)src, f1 = *(const float4*)(src + 4);
            union { ushort u[8]; uint4 v; } pk;
            pk.u[0] = f2bf(f0.x); pk.u[1] = f2bf(f0.y); pk.u[2] = f2bf(f0.z); pk.u[3] = f2bf(f0.w);
            pk.u[4] = f2bf(f1.x); pk.u[5] = f2bf(f1.y); pk.u[6] = f2bf(f1.z); pk.u[7] = f2bf(f1.w);
            *(uint4*)&tbl[r * 40 + part * 8] = pk.v;
        }
        for (int e = tid; e < (Rpad - R) * 40; e += 256) tbl[R * 40 + e] = 0;
    };
    // No zero-pad needed: per-c value-bias reads only cols < c*T+T <= 120.
    auto stageVtbl = [&](const float* tbg, int R) {
        for (int e = tid; e < R * 4; e += 256) {
            int r = e >> 2, part = e & 3;
            const float* src = tbg + (size_t)r * 256 + part * 8;
            float4 f0 = *(const float4*)src, f1 = *(const float4*)(src + 4);
            int d0 = part * 8;
            vtbl[(d0 + 0) * 136 + r] = f2bf(f0.x);
            vtbl[(d0 + 1) * 136 + r] = f2bf(f0.y);
            vtbl[(d0 + 2) * 136 + r] = f2bf(f0.z);
            vtbl[(d0 + 3) * 136 + r] = f2bf(f0.w);
            vtbl[(d0 + 4) * 136 + r] = f2bf(f1.x);
            vtbl[(d0 + 5) * 136 + r] = f2bf(f1.y);
            vtbl[(d0 + 6) * 136 + r] = f2bf(f1.z);
            vtbl[(d0 + 7) * 136 + r] = f2bf(f1.w);
        }
    };
    auto stageVt = [&]() {
        int j = tid >> 2, d0 = (tid & 3) * 8;
        uint4 pk = *(const uint4*)(vb + base + tid * 8);
        const ushort* u = (const ushort*)&pk;
#pragma unroll
        for (int ii = 0; ii < 8; ++ii) v_t[(d0 + ii) * 72 + j] = u[ii];
    };

    float lg[4][4];   // [tt][reg]: row i = w*16+quad*4+reg, col j = tt*16+l4

    // table-GEMM for component c: contracts a_s rows with tbl rows
    // [c*T, c*T+T), writing the T local bins into dbuf cols [0, T).
    auto tgemmC = [&](const ushort* a_s, int c, int T) {
        short8 af = *(const short8*)&a_s[(w * 16 + l4) * 40 + quad * 8];
        const int NT = (T == 40) ? 3 : 2;
        for (int tt = 0; tt < NT; ++tt) {
            short8 bf = *(const short8*)&tbl[(c * T + tt * 16 + l4) * 40 + quad * 8];
            f32x4 a = {0.f, 0.f, 0.f, 0.f};
            a = __builtin_amdgcn_mfma_f32_16x16x32_bf16(af, bf, a, 0, 0, 0);
            int col = tt * 16 + l4;
            int rb = w * 16 + quad * 4;
            if (col < T) {
                dbuf[(rb + 0) * DBS + col] = a[0];
                dbuf[(rb + 1) * DBS + col] = a[1];
                dbuf[(rb + 2) * DBS + col] = a[2];
                dbuf[(rb + 3) * DBS + col] = a[3];
            }
        }
    };
    // Indices recomputed from cwf at every use site (no idx register arrays).
    auto gatherC = [&](int cc, int off, int hi, bool useJ) {
#pragma unroll
        for (int tt = 0; tt < 4; ++tt) {
            int j = tt * 16 + l4;
            float cj = cwf[j * 6 + cc];
#pragma unroll
            for (int reg = 0; reg < 4; ++reg) {
                int i = w * 16 + quad * 4 + reg;
                int x = min(max((int)floorf(cwf[i * 6 + cc] - cj) + off, 0), hi);
                lg[tt][reg] += dbuf[(useJ ? j : i) * DBS + x];
            }
        }
    };
    auto scatterC = [&](int cc, int off, int hi) {
#pragma unroll
        for (int tt = 0; tt < 4; ++tt) {
            int j = tt * 16 + l4;
            float cj = cwf[j * 6 + cc];
#pragma unroll
            for (int reg = 0; reg < 4; ++reg) {
                int i = w * 16 + quad * 4 + reg;
                int x = min(max((int)floorf(cwf[i * 6 + cc] - cj) + off, 0), hi);
                atomicAdd(&dbuf[i * DBS + x], lg[tt][reg]);
            }
        }
    };
    // zero this wave's 16 bin rows only (wave-private)
    auto zeroOwn = [&]() {
        float* rb = &dbuf[w * 16 * DBS];
        for (int e = lane; e < 16 * DBS; e += 64) rb[e] = 0.f;
    };

    stageTbl(kxt + h * 32, 120, 128);
    __syncthreads();

    // ---- QK logits ----
    {
        short8 aq = *(const short8*)&q_s[(w * 16 + l4) * 40 + quad * 8];
#pragma unroll
        for (int tt = 0; tt < 4; ++tt) {
            short8 bk = *(const short8*)&k_s[(tt * 16 + l4) * 40 + quad * 8];
            f32x4 r = {0.f, 0.f, 0.f, 0.f};
            r = __builtin_amdgcn_mfma_f32_16x16x32_bf16(aq, bk, r, 0, 0, 0);
            lg[tt][0] = r[0]; lg[tt][1] = r[1]; lg[tt][2] = r[2]; lg[tt][3] = r[3];
        }
    }

    // ---- dk (bias_k): cross-wave j-row gathers -> real barriers ----
    tgemmC(k_s, 0, 40);
    __syncthreads();
    gatherC(0, 20, 39, true);
    __syncthreads();
    tgemmC(k_s, 1, 40);
    __syncthreads();
    gatherC(1, 20, 39, true);
    __syncthreads();
    tgemmC(k_s, 2, 40);
    __syncthreads();
    gatherC(2, 20, 39, true);
    stageTbl(krt + h * 32, 96, 96);
    __syncthreads();
    tgemmC(k_s, 0, 32);
    __syncthreads();
    gatherC(3, 16, 31, true);
    __syncthreads();
    tgemmC(k_s, 1, 32);
    __syncthreads();
    gatherC(4, 16, 31, true);
    __syncthreads();
    tgemmC(k_s, 2, 32);
    __syncthreads();
    gatherC(5, 16, 31, true);
    stageTbl(qxt + h * 32, 120, 128);
    __syncthreads();

    // ---- dq (bias_q): wave-private i-rows -> fences only ----
    tgemmC(q_s, 0, 40); LFENCE();
    gatherC(0, 20, 39, false); LFENCE();
    tgemmC(q_s, 1, 40); LFENCE();
    gatherC(1, 20, 39, false); LFENCE();
    tgemmC(q_s, 2, 40);
    __syncthreads();                       // others must finish reading tbl
    gatherC(2, 20, 39, false);
    stageTbl(qrt + h * 32, 96, 96);
    __syncthreads();
    tgemmC(q_s, 0, 32); LFENCE();
    gatherC(3, 16, 31, false); LFENCE();
    tgemmC(q_s, 1, 32); LFENCE();
    gatherC(4, 16, 31, false); LFENCE();
    tgemmC(q_s, 2, 32);
    __syncthreads();                       // tbl/k_s regions go dead here
    gatherC(5, 16, 31, false);
    stageVtbl(vxt + h * 32, 120);
    stageVt();
    __syncthreads();

    // ---- softmax ----
#pragma unroll
    for (int reg = 0; reg < 4; ++reg) {
        float m = fmaxf(fmaxf(lg[0][reg], lg[1][reg]), fmaxf(lg[2][reg], lg[3][reg]));
        m = fmaxf(m, __shfl_xor(m, 1));
        m = fmaxf(m, __shfl_xor(m, 2));
        m = fmaxf(m, __shfl_xor(m, 4));
        m = fmaxf(m, __shfl_xor(m, 8));
        float s = 0.f;
#pragma unroll
        for (int tt = 0; tt < 4; ++tt) { lg[tt][reg] = __expf(lg[tt][reg] - m); s += lg[tt][reg]; }
        s += __shfl_xor(s, 1); s += __shfl_xor(s, 2);
        s += __shfl_xor(s, 4); s += __shfl_xor(s, 8);
        float inv = 1.f / s;
#pragma unroll
        for (int tt = 0; tt < 4; ++tt) lg[tt][reg] *= inv;
    }
#pragma unroll
    for (int tt = 0; tt < 4; ++tt)
#pragma unroll
        for (int reg = 0; reg < 4; ++reg)
            attn_s[(w * 16 + quad * 4 + reg) * 72 + tt * 16 + l4] = f2bf(lg[tt][reg]);
    zeroOwn();
    __syncthreads();

    // ---- AV ----
    f32x4 acc0 = {0.f, 0.f, 0.f, 0.f}, acc1 = {0.f, 0.f, 0.f, 0.f};
#pragma unroll
    for (int s = 0; s < 2; ++s) {
        short8 af = *(const short8*)&attn_s[(w * 16 + l4) * 72 + s * 32 + quad * 8];
        short8 b0 = *(const short8*)&v_t[l4 * 72 + s * 32 + quad * 8];
        short8 b1 = *(const short8*)&v_t[(16 + l4) * 72 + s * 32 + quad * 8];
        acc0 = __builtin_amdgcn_mfma_f32_16x16x32_bf16(af, b0, acc0, 0, 0, 0);
        acc1 = __builtin_amdgcn_mfma_f32_16x16x32_bf16(af, b1, acc1, 0, 0, 0);
    }

    // value-bias contraction for component c: bins cols [0,T) x vtbl cols
    // [c*T, c*T+T). A-frag rows are wave-private.
    auto atgemmC = [&](int c, int T, int S) {
#pragma unroll
        for (int s = 0; s < S; ++s) {
            int koff = s * 32 + quad * 8;
            short8 af = {0, 0, 0, 0, 0, 0, 0, 0};
            int kr = 0;
            if (koff < T) {
                const float* ap = &dbuf[(w * 16 + l4) * DBS + koff];
#pragma unroll
                for (int ii = 0; ii < 8; ++ii) af[ii] = (short)f2bf(ap[ii]);
                kr = c * T + koff;
            }
            short8 b0 = *(const short8*)&vtbl[l4 * 136 + kr];
            short8 b1 = *(const short8*)&vtbl[(16 + l4) * 136 + kr];
            acc0 = __builtin_amdgcn_mfma_f32_16x16x32_bf16(af, b0, acc0, 0, 0, 0);
            acc1 = __builtin_amdgcn_mfma_f32_16x16x32_bf16(af, b1, acc1, 0, 0, 0);
        }
    };

    // ---- value-bias xyz: all dbuf traffic wave-private -> fences only ----
    scatterC(0, 20, 39); LFENCE();
    atgemmC(0, 40, 2); LFENCE();
    zeroOwn(); LFENCE();
    scatterC(1, 20, 39); LFENCE();
    atgemmC(1, 40, 2); LFENCE();
    zeroOwn(); LFENCE();
    scatterC(2, 20, 39); LFENCE();
    atgemmC(2, 40, 2);
    __syncthreads();                       // all waves done reading vtbl(vxt)
    zeroOwn();
    stageVtbl(vrt + h * 32, 96);
    __syncthreads();

    // ---- value-bias rgb ----
    scatterC(3, 16, 31); LFENCE();
    atgemmC(0, 32, 1); LFENCE();
    zeroOwn(); LFENCE();
    scatterC(4, 16, 31); LFENCE();
    atgemmC(1, 32, 1); LFENCE();
    zeroOwn(); LFENCE();
    scatterC(5, 16, 31); LFENCE();
    atgemmC(2, 32, 1);

    // ---- epilogue: bf16 ao[i][h*32+d] ----
    {
        ushort* op = aout + (size_t)(n * 64 + w * 16 + quad * 4) * 256 + h * 32;
#pragma unroll
        for (int reg = 0; reg < 4; ++reg) {
            op[reg * 256 + l4] = f2bf(acc0[reg]);
            op[reg * 256 + 16 + l4] = f2bf(acc1[reg]);
        }
    }
}

// ---------------------------------------------------------------------------
// Proj GEMM (bf16 MFMA): out = ao(bf16) @ proj_w(fp32, cast inline)^T + pb
// ---------------------------------------------------------------------------
__global__ __launch_bounds__(256) void k_proj(
    const ushort* __restrict__ A, const float* __restrict__ B,
    const float* __restrict__ bias, float* __restrict__ out)
{
    __shared__ __align__(16) ushort a_s[128 * 72];
    __shared__ __align__(16) ushort b_s[64 * 72];
    const int tid = threadIdx.x;
    const int m0 = blockIdx.y * 128;
    const int n0 = blockIdx.x * 64;
    const int w = tid >> 6, wm = w >> 1, wn = w & 1;
    const int l4 = tid & 15, quad = (tid >> 4) & 3;
    f32x4 acc[4][2];
#pragma unroll
    for (int mt = 0; mt < 4; ++mt)
#pragma unroll
        for (int nt = 0; nt < 2; ++nt) acc[mt][nt] = (f32x4){0.f, 0.f, 0.f, 0.f};

    for (int k0 = 0; k0 < 256; k0 += 64) {
#pragma unroll
        for (int l = 0; l < 4; ++l) {
            int e = tid + l * 256;
            int row = e >> 3, kq = e & 7;
            *(uint4*)&a_s[row * 72 + kq * 8] =
                *(const uint4*)(A + (size_t)(m0 + row) * 256 + k0 + kq * 8);
        }
#pragma unroll
        for (int l = 0; l < 2; ++l) {
            int e = tid + l * 256;
            int row = e >> 3, kq = e & 7;
            const float* bp = B + (size_t)(n0 + row) * 256 + k0 + kq * 8;
            float4 v0 = *(const float4*)bp, v1 = *(const float4*)(bp + 4);
            union { ushort u[8]; uint4 v; } pk;
            pk.u[0] = f2bf(v0.x); pk.u[1] = f2bf(v0.y); pk.u[2] = f2bf(v0.z); pk.u[3] = f2bf(v0.w);
            pk.u[4] = f2bf(v1.x); pk.u[5] = f2bf(v1.y); pk.u[6] = f2bf(v1.z); pk.u[7] = f2bf(v1.w);
            *(uint4*)&b_s[row * 72 + kq * 8] = pk.v;
        }
        __syncthreads();
#pragma unroll
        for (int kh = 0; kh < 2; ++kh) {
            short8 bf0 = *(const short8*)&b_s[(wn * 32 + l4) * 72 + kh * 32 + quad * 8];
            short8 bf1 = *(const short8*)&b_s[(wn * 32 + 16 + l4) * 72 + kh * 32 + quad * 8];
#pragma unroll
            for (int mt = 0; mt < 4; ++mt) {
                short8 af = *(const short8*)&a_s[(wm * 64 + mt * 16 + l4) * 72 + kh * 32 + quad * 8];
                acc[mt][0] = __builtin_amdgcn_mfma_f32_16x16x32_bf16(af, bf0, acc[mt][0], 0, 0, 0);
                acc[mt][1] = __builtin_amdgcn_mfma_f32_16x16x32_bf16(af, bf1, acc[mt][1], 0, 0, 0);
            }
        }
        __syncthreads();
    }
#pragma unroll
    for (int nt = 0; nt < 2; ++nt) {
        int c = n0 + wn * 32 + nt * 16 + l4;
        float bv = bias[c];
#pragma unroll
        for (int mt = 0; mt < 4; ++mt) {
            int mbase = m0 + wm * 64 + mt * 16 + quad * 4;
#pragma unroll
            for (int reg = 0; reg < 4; ++reg)
                out[(size_t)(mbase + reg) * 256 + c] = acc[mt][nt][reg] + bv;
        }
    }
}

extern "C" void kernel_launch(void* const* d_in, const int* in_sizes, int n_in,
                              void* d_out, int out_size, void* d_ws, size_t ws_size,
                              hipStream_t stream)
{
    const float* feats = (const float*)d_in[0];
    const float* nco   = (const float*)d_in[1];
    const float* qkvw  = (const float*)d_in[2];
    const float* qkvb  = (const float*)d_in[3];
    const float* qxt   = (const float*)d_in[4];
    const float* kxt   = (const float*)d_in[5];
    const float* vxt   = (const float*)d_in[6];
    const float* qrt   = (const float*)d_in[7];
    const float* krt   = (const float*)d_in[8];
    const float* vrt   = (const float*)d_in[9];
    const float* pw    = (const float*)d_in[10];
    const float* pb    = (const float*)d_in[11];
    float* out = (float*)d_out;

    ushort* qb  = (ushort*)d_ws;                       // [128][8][64][32] bf16
    ushort* kb  = qb + (size_t)2097152;
    ushort* vb  = kb + (size_t)2097152;
    ushort* aob = vb + (size_t)2097152;                // [8192][256] bf16

    k_qkv<<<dim3(12, 64), 256, 0, stream>>>(feats, qkvw, qkvb, qb, kb, vb);
    k_attn<<<dim3(1024), 256, 0, stream>>>(qb, kb, vb, nco, qxt, kxt, vxt, qrt, krt, vrt, aob);
    k_proj<<<dim3(4, 64), 256, 0, stream>>>(aob, pw, pb, out);
}